// Round 11
// baseline (396.800 us; speedup 1.0000x reference)
//
#include <hip/hip_runtime.h>
#include <math.h>

// Problem dims (fixed by reference)
#define B_   4
#define L_   1024
#define D_   512
#define CHI_ 32
#define S_   4
#define BT_  (B_ * L_)          // 4096 rows
#define NC_  2560               // fused GEMM width: 1024 AbarI | 1024 G | 512 gate
#define DPRE 8                  // scan prefetch distance (register ring)

// ---------------------------------------------------------------------------
// Cross-lane helpers
// ---------------------------------------------------------------------------
__device__ __forceinline__ float readlane_f(float v, int l) {
    return __int_as_float(__builtin_amdgcn_readlane(__float_as_int(v), l));
}

__device__ __forceinline__ float bpermute_f(int byte_idx, float v) {
    return __int_as_float(__builtin_amdgcn_ds_bpermute(byte_idx, __float_as_int(v)));
}

template <int CTRL>
__device__ __forceinline__ float dpp_add(float x) {
    int y = __builtin_amdgcn_update_dpp(0, __float_as_int(x), CTRL, 0xf, 0xf, true);
    return x + __int_as_float(y);
}

// Sum of lanes 0..31, valid in lane 31 (row_shr moves toward HIGHER lanes).
__device__ __forceinline__ float reduce32_to_lane31(float x) {
    x = dpp_add<0x111>(x);
    x = dpp_add<0x112>(x);
    x = dpp_add<0x114>(x);
    x = dpp_add<0x118>(x);
    x = dpp_add<0x142>(x);  // row_bcast15 -> lane31
    return x;
}

// Octet sum; complete sum lands in the TOP lane of each octet ((lane&7)==7).
__device__ __forceinline__ float octet_sum(float x) {
    x = dpp_add<0x111>(x);
    x = dpp_add<0x112>(x);
    x = dpp_add<0x114>(x);
    return x;
}

// ---------------------------------------------------------------------------
// buildW: fold W_site with (sum_p ·) and with W_bridge; append W_gate.
//   Wcomb[d][f], f in [0,1024):    WA_perm  (scan-interleaved Abar columns)
//   f in [1024,2048):              WW[l*32+j] = sum_pr Ws[d,l*128+pr]*Wb[pr,j]
//   f in [2048,2560):              W_gate[d][f-2048]
// Block 512 == bias block (same folds applied to b_site / b_gate).
// Interleave map: f = 256q+4i+e  ->  l = 4*(i&7)+e,  r = (i>>3)+8q.
// ---------------------------------------------------------------------------
__global__ __launch_bounds__(256) void buildW_kernel(
    const float* __restrict__ Ws, const float* __restrict__ bs,
    const float* __restrict__ Wb, const float* __restrict__ Wg,
    const float* __restrict__ bg, float* __restrict__ Wcomb,
    float* __restrict__ biasC)
{
    const int tid = threadIdx.x;

    if (blockIdx.x == 512) {   // bias block
        for (int f = tid; f < NC_; f += 256) {
            float acc;
            if (f < 1024) {
                const int q = f >> 8, rem = f & 255, i = rem >> 2, e = rem & 3;
                const int l = 4 * (i & 7) + e, r = (i >> 3) + 8 * q;
                const float* p = bs + l * 128 + r;
                acc = p[0] + p[32] + p[64] + p[96];
            } else if (f < 2048) {
                const int g = f - 1024, l = g >> 5, j = g & 31;
                acc = 0.f;
                for (int pr = 0; pr < 128; ++pr)
                    acc = fmaf(bs[l * 128 + pr], Wb[pr * 32 + j], acc);
            } else {
                acc = bg[f - 2048];
            }
            biasC[f] = acc;
        }
        return;
    }

    __shared__ float wsrow[4096];
    __shared__ float wbs[4096];    // Wb[pr][j], pr*32+j

    const int d = blockIdx.x;
    #pragma unroll
    for (int i = 0; i < 16; ++i) {
        wsrow[i * 256 + tid] = Ws[(size_t)d * 4096 + i * 256 + tid];
        wbs[i * 256 + tid]   = Wb[i * 256 + tid];
    }
    __syncthreads();

    float* wrow = Wcomb + (size_t)d * NC_;

    // WA (interleaved): 4 cols/thread
    #pragma unroll
    for (int ii = 0; ii < 4; ++ii) {
        const int f = ii * 256 + tid;
        const int q = f >> 8, rem = f & 255, i = rem >> 2, e = rem & 3;
        const int l = 4 * (i & 7) + e, r = (i >> 3) + 8 * q;
        const float* p = wsrow + l * 128 + r;
        wrow[f] = p[0] + p[32] + p[64] + p[96];
    }
    // WW: 4 cols/thread, 128 FMA each
    #pragma unroll
    for (int ii = 0; ii < 4; ++ii) {
        const int g = ii * 256 + tid;
        const int l = g >> 5, j = g & 31;
        float acc = 0.f;
        #pragma unroll 8
        for (int pr = 0; pr < 128; ++pr)
            acc = fmaf(wsrow[l * 128 + pr], wbs[pr * 32 + j], acc);
        wrow[1024 + g] = acc;
    }
    // gate copy: 2 cols/thread
    #pragma unroll
    for (int ii = 0; ii < 2; ++ii) {
        const int c = ii * 256 + tid;
        wrow[2048 + c] = Wg[(size_t)d * 512 + c];
    }
}

// ---------------------------------------------------------------------------
// GEMM tile body (shared by part-1 kernel and the fused kernel).
// 128x128 tile, 256 threads, 8x8 acc/thread, BK=32 (single-buffer LDS).
// As stored transposed [k][m] (pad 132 -> 16B-aligned rows, float4 reads).
// ---------------------------------------------------------------------------
__device__ __forceinline__ void gemm_tile_body(
    const float* __restrict__ A, const float* __restrict__ Bm,
    const float* __restrict__ bias, float* __restrict__ C,
    int M, int N, int K, int m0, int n0,
    float (*As)[132], float (*Bs)[132])
{
    const int tid = threadIdx.x;
    const int tx = tid & 15;        // col group (n)
    const int ty = tid >> 4;        // row group (m)

    float acc[8][8] = {};

    for (int k0 = 0; k0 < K; k0 += 32) {
        // A tile: 128 rows x 32 k, write transposed As[k][m]
        #pragma unroll
        for (int p = 0; p < 4; ++p) {
            const int m = (tid >> 3) + 32 * p;
            const int k = (tid & 7) * 4;
            const float4 av = *(const float4*)(A + (size_t)(m0 + m) * K + k0 + k);
            As[k + 0][m] = av.x;
            As[k + 1][m] = av.y;
            As[k + 2][m] = av.z;
            As[k + 3][m] = av.w;
        }
        // B tile: 32 k x 128 n
        #pragma unroll
        for (int p = 0; p < 2; ++p) {
            const int k = (tid >> 4) + 16 * p;
            const int n = (tid & 15) * 8;
            const float* bp = Bm + (size_t)(k0 + k) * N + n0 + n;
            *(float4*)&Bs[k][n]     = *(const float4*)bp;
            *(float4*)&Bs[k][n + 4] = *(const float4*)(bp + 4);
        }
        __syncthreads();

        #pragma unroll
        for (int kk = 0; kk < 32; ++kk) {
            const float4 a0 = *(const float4*)&As[kk][ty * 8];
            const float4 a1 = *(const float4*)&As[kk][ty * 8 + 4];
            const float4 b0 = *(const float4*)&Bs[kk][tx * 8];
            const float4 b1 = *(const float4*)&Bs[kk][tx * 8 + 4];
            const float a[8] = {a0.x, a0.y, a0.z, a0.w, a1.x, a1.y, a1.z, a1.w};
            const float b[8] = {b0.x, b0.y, b0.z, b0.w, b1.x, b1.y, b1.z, b1.w};
            #pragma unroll
            for (int i = 0; i < 8; ++i)
                #pragma unroll
                for (int j = 0; j < 8; ++j)
                    acc[i][j] = fmaf(a[i], b[j], acc[i][j]);
        }
        __syncthreads();
    }

    const float4 bv0 = *(const float4*)&bias[n0 + tx * 8];
    const float4 bv1 = *(const float4*)&bias[n0 + tx * 8 + 4];
    #pragma unroll
    for (int i = 0; i < 8; ++i) {
        float* cp = C + (size_t)(m0 + ty * 8 + i) * N + n0 + tx * 8;
        float4 o0, o1;
        o0.x = acc[i][0] + bv0.x; o0.y = acc[i][1] + bv0.y;
        o0.z = acc[i][2] + bv0.z; o0.w = acc[i][3] + bv0.w;
        o1.x = acc[i][4] + bv1.x; o1.y = acc[i][5] + bv1.y;
        o1.z = acc[i][6] + bv1.z; o1.w = acc[i][7] + bv1.w;
        *(float4*)cp       = o0;
        *(float4*)(cp + 4) = o1;
    }
}

// Part 1: C columns [0, 1024)  (AbarI block, needed by the scan)
__global__ __launch_bounds__(256) void gemm_bias_kernel(
    const float* __restrict__ A, const float* __restrict__ Bm,
    const float* __restrict__ bias, float* __restrict__ C,
    int M, int N, int K)
{
    __shared__ float As[32][132];
    __shared__ float Bs[32][132];
    gemm_tile_body(A, Bm, bias, C, M, N, K,
                   blockIdx.y * 128, blockIdx.x * 128, As, Bs);
}

// ---------------------------------------------------------------------------
// FUSED: serial scan (blocks 0..3, tid<64) + GEMM part 2 (blocks 4..387,
// C columns [1024, 2560) = G + gate). The scan reads C cols [0,1024) and x
// (both finalized); the GEMM writes cols [1024,2560) -- fully disjoint, no
// inter-block dependency. The 384 GEMM blocks fill the CUs idle during the
// scan.
//
// Scan, LEFT-FORM recurrence (mathematically identical to the verified
// w' = (w.Abar)*rn + c form by distributivity, with c_t = u_t.Abar_t
// folded in -- eliminates the former cvec kernel entirely):
//   rn   = rsqrt(sum w^2 + 1e-24)
//   left = w*rn + u_t            (per-lane fma; u_t = x[b,t, lane&31])
//   w'   = left . Abar_t         (same bpermute/octet/bpermute machinery)
// wOut stores pre-norm w_t (unchanged semantics for phaseB).
// ---------------------------------------------------------------------------
__global__ __launch_bounds__(256) void fused_scan_gemm2_kernel(
    const float* __restrict__ x, const float* __restrict__ Wcomb,
    const float* __restrict__ biasC, float* __restrict__ Cc,
    float* __restrict__ wOut)
{
    __shared__ float As[32][132];
    __shared__ float Bs[32][132];

    if (blockIdx.x < 4) {
        // ------------------ scan path (threads 0..63 only) ------------------
        const int tid = threadIdx.x;
        if (tid >= 64) return;
        const int b = blockIdx.x;

        const float* At = Cc + (size_t)b * L_ * NC_ + 4 * tid;   // lane base
        const float* xr = x  + (size_t)b * L_ * D_ + (tid & 31); // u_t source
        float*       wo = wOut + (size_t)b * L_ * 64 + tid;

        const int idx0 = 16 * (tid & 7);
        const int idxR = 32 * (tid & 7) + 28;    // octet TOP lane
        const bool selA = (tid >> 3) & 1;
        const bool selB = (tid >> 4) & 1;

        float4 areg[DPRE][4];
        float  xreg[DPRE];

        #pragma unroll
        for (int j = 0; j < DPRE; ++j) {
            const float* ap = At + (size_t)j * NC_;
            #pragma unroll
            for (int q = 0; q < 4; ++q) areg[j][q] = *(const float4*)(ap + 256 * q);
            xreg[j] = xr[(size_t)j * D_];
        }

        float w = 0.f;   // w_0 = 0  (h_0 = 0 -> left_0 = u_0)

        for (int t = 0; t < L_; t += DPRE) {
            #pragma unroll
            for (int j = 0; j < DPRE; ++j) {
                wo[(t + j) * 64] = w;

                float red = reduce32_to_lane31(w * w);
                const float n2 = readlane_f(red, 31);
                const float rn = rsqrtf(n2 + 1e-24f);
                const float lft = fmaf(w, rn, xreg[j]);   // left = h + u

                const float lb0 = bpermute_f(idx0 + 0,  lft);
                const float lb1 = bpermute_f(idx0 + 4,  lft);
                const float lb2 = bpermute_f(idx0 + 8,  lft);
                const float lb3 = bpermute_f(idx0 + 12, lft);

                float p0, p1, p2, p3;
                {
                    const float4 a0 = areg[j][0], a1 = areg[j][1];
                    const float4 a2 = areg[j][2], a3 = areg[j][3];
                    p0 = fmaf(lb3, a0.w, fmaf(lb2, a0.z, fmaf(lb1, a0.y, lb0 * a0.x)));
                    p1 = fmaf(lb3, a1.w, fmaf(lb2, a1.z, fmaf(lb1, a1.y, lb0 * a1.x)));
                    p2 = fmaf(lb3, a2.w, fmaf(lb2, a2.z, fmaf(lb1, a2.y, lb0 * a2.x)));
                    p3 = fmaf(lb3, a3.w, fmaf(lb2, a3.z, fmaf(lb1, a3.y, lb0 * a3.x)));
                }

                p0 = octet_sum(p0);
                p1 = octet_sum(p1);
                p2 = octet_sum(p2);
                p3 = octet_sum(p3);

                const float m0 = bpermute_f(idxR, p0);
                const float m1 = bpermute_f(idxR, p1);
                const float m2 = bpermute_f(idxR, p2);
                const float m3 = bpermute_f(idxR, p3);
                const float t0 = selA ? m1 : m0;
                const float t1 = selA ? m3 : m2;
                w = selB ? t1 : t0;                        // w_{t+1} = left.Abar

                int tn = t + j + DPRE;
                if (tn > L_ - 1) tn = L_ - 1;
                const float* ap = At + (size_t)tn * NC_;
                #pragma unroll
                for (int q = 0; q < 4; ++q) areg[j][q] = *(const float4*)(ap + 256 * q);
                xreg[j] = xr[(size_t)tn * D_];
            }
        }
        return;
    }

    // ------------------ GEMM part-2 path (cols 1024..2560) ------------------
    const int g  = blockIdx.x - 4;
    const int m0 = (g / 12) * 128;
    const int n0 = 1024 + (g % 12) * 128;
    gemm_tile_body(x, Wcomb, biasC, Cc, BT_, NC_, D_, m0, n0, As, Bs);
}

// ---------------------------------------------------------------------------
// FUSED phaseB + epilogue (one block per bt, 256 threads):
//   lf = w/||w|| + u                       (threads 0..63)
//   y1[j] = sum_l lf[l]*G[l*32+j] + bb[j]  (8 groups x 32, G in C cols 1024+)
//   y = y1 @ W_out + b_out; LayerNorm; gated residual (gate from C cols 2048+)
// ---------------------------------------------------------------------------
__global__ __launch_bounds__(256) void phaseB_epilogue_kernel(
    const float* __restrict__ Cc, const float* __restrict__ x,
    const float* __restrict__ wBuf, const float* __restrict__ bb,
    const float* __restrict__ Wout, const float* __restrict__ bout,
    const float* __restrict__ gamma, const float* __restrict__ beta,
    float* __restrict__ out)
{
    __shared__ float lf[32];
    __shared__ float part[8][32];
    __shared__ float ys[32];
    __shared__ float red1[4], red2[4];

    const int bt = blockIdx.x;
    const int tid = threadIdx.x;

    if (tid < 64) {
        const float wv = wBuf[(size_t)bt * 64 + tid];
        float red = reduce32_to_lane31(wv * wv);
        const float n2 = readlane_f(red, 31);
        const float rn = rsqrtf(n2 + 1e-24f);
        if (tid < 32)
            lf[tid] = fmaf(wv, rn, x[(size_t)bt * D_ + tid]);  // left = h + u
    }
    __syncthreads();

    {
        const int j = tid & 31, q = tid >> 5;   // q in 0..7, 4 l's each
        const float* Gp = Cc + (size_t)bt * NC_ + 1024;
        float p = 0.f;
        #pragma unroll
        for (int i = 0; i < 4; ++i)
            p = fmaf(lf[4 * q + i], Gp[(4 * q + i) * 32 + j], p);
        part[q][j] = p;
    }
    __syncthreads();

    if (tid < 32) {
        float s = bb[tid];
        #pragma unroll
        for (int q = 0; q < 8; ++q) s += part[q][tid];
        ys[tid] = s;
    }
    __syncthreads();

    float yv[2];
    #pragma unroll
    for (int q = 0; q < 2; ++q) {
        const int d = tid + q * 256;
        float acc = bout[d];
        #pragma unroll
        for (int j = 0; j < 32; ++j)
            acc = fmaf(ys[j], Wout[j * D_ + d], acc);
        yv[q] = acc;
    }

    float s1 = yv[0] + yv[1];
    float s2 = yv[0] * yv[0] + yv[1] * yv[1];
    #pragma unroll
    for (int m = 1; m <= 32; m <<= 1) {
        s1 += __shfl_xor(s1, m);
        s2 += __shfl_xor(s2, m);
    }
    const int wid = tid >> 6;
    if ((tid & 63) == 0) { red1[wid] = s1; red2[wid] = s2; }
    __syncthreads();
    const float S1 = red1[0] + red1[1] + red1[2] + red1[3];
    const float S2 = red2[0] + red2[1] + red2[2] + red2[3];
    const float mu  = S1 * (1.f / (float)D_);
    const float var = S2 * (1.f / (float)D_) - mu * mu;
    const float rstd = rsqrtf(var + 1e-6f);

    #pragma unroll
    for (int q = 0; q < 2; ++q) {
        const int d = tid + q * 256;
        const size_t gi = (size_t)bt * D_ + d;
        const float yn = (yv[q] - mu) * rstd * gamma[d] + beta[d];
        const float z = Cc[(size_t)bt * NC_ + 2048 + d];
        const float g = 1.f / (1.f + expf(-z));
        const float xv = x[gi];
        out[gi] = g * yn + (1.f - g) * xv;
    }
}

// ---------------------------------------------------------------------------
extern "C" void kernel_launch(void* const* d_in, const int* in_sizes, int n_in,
                              void* d_out, int out_size, void* d_ws, size_t ws_size,
                              hipStream_t stream)
{
    const float* x        = (const float*)d_in[0];
    const float* W_site   = (const float*)d_in[1];
    const float* b_site   = (const float*)d_in[2];
    const float* W_bridge = (const float*)d_in[3];
    const float* b_bridge = (const float*)d_in[4];
    const float* W_out    = (const float*)d_in[5];
    const float* b_out    = (const float*)d_in[6];
    const float* gamma    = (const float*)d_in[7];
    const float* beta     = (const float*)d_in[8];
    const float* W_gate   = (const float*)d_in[9];
    const float* b_gate   = (const float*)d_in[10];
    float* out = (float*)d_out;

    float* ws = (float*)d_ws;
    float* Wcomb = ws;                            //   512*2560 = 1,310,720 f
    float* biasC = Wcomb + (size_t)512 * NC_;     //        2,560 f
    float* Cc    = biasC + NC_;                   // 4096*2560 = 10,485,760 f (42 MB)
    float* wBuf  = Cc    + (size_t)BT_ * NC_;     //      262,144 f

    // 0. fold weights: [WA_perm | WW | W_gate] + fused bias
    buildW_kernel<<<dim3(513), dim3(256), 0, stream>>>(
        W_site, b_site, W_bridge, W_gate, b_gate, Wcomb, biasC);

    // 1. GEMM part 1: C cols [0,1024) = AbarI   [4096 x 1024, K=512]
    gemm_bias_kernel<<<dim3(8, BT_ / 128), dim3(256), 0, stream>>>(
        x, Wcomb, biasC, Cc, BT_, NC_, D_);

    // 2. FUSED: scan (blocks 0..3, left-form recurrence -- cvec folded in)
    //    + GEMM part 2 (cols 1024..2560, blocks 4..387) on the idle CUs.
    fused_scan_gemm2_kernel<<<dim3(4 + 12 * (BT_ / 128)), dim3(256), 0, stream>>>(
        x, Wcomb, biasC, Cc, wBuf);

    // 3. FUSED phaseB + epilogue
    phaseB_epilogue_kernel<<<dim3(BT_), dim3(256), 0, stream>>>(
        Cc, x, wBuf, b_bridge, W_out, b_out, gamma, beta, out);
}

// Round 12
// 389.548 us; speedup vs baseline: 1.0186x; 1.0186x over previous
//
#include <hip/hip_runtime.h>
#include <math.h>

// Problem dims (fixed by reference)
#define B_   4
#define L_   1024
#define D_   512
#define CHI_ 32
#define S_   4
#define BT_  (B_ * L_)          // 4096 rows
#define NC_  2560               // fused GEMM width: 1024 AbarI | 1024 G | 512 gate
#define DPRE 8                  // scan prefetch distance (register ring)

// ---------------------------------------------------------------------------
// Cross-lane helpers
// ---------------------------------------------------------------------------
__device__ __forceinline__ float readlane_f(float v, int l) {
    return __int_as_float(__builtin_amdgcn_readlane(__float_as_int(v), l));
}

__device__ __forceinline__ float bpermute_f(int byte_idx, float v) {
    return __int_as_float(__builtin_amdgcn_ds_bpermute(byte_idx, __float_as_int(v)));
}

template <int CTRL>
__device__ __forceinline__ float dpp_add(float x) {
    int y = __builtin_amdgcn_update_dpp(0, __float_as_int(x), CTRL, 0xf, 0xf, true);
    return x + __int_as_float(y);
}

// Sum of lanes 0..31, valid in lane 31 (row_shr moves toward HIGHER lanes).
__device__ __forceinline__ float reduce32_to_lane31(float x) {
    x = dpp_add<0x111>(x);
    x = dpp_add<0x112>(x);
    x = dpp_add<0x114>(x);
    x = dpp_add<0x118>(x);
    x = dpp_add<0x142>(x);  // row_bcast15 -> lane31
    return x;
}

// Octet sum; complete sum lands in the TOP lane of each octet ((lane&7)==7).
__device__ __forceinline__ float octet_sum(float x) {
    x = dpp_add<0x111>(x);
    x = dpp_add<0x112>(x);
    x = dpp_add<0x114>(x);
    return x;
}

// ---------------------------------------------------------------------------
// buildW: fold W_site with (sum_p ·) and with W_bridge; append W_gate.
//   Wcomb[d][f], f in [0,1024):    WA_perm  (scan-interleaved Abar columns)
//   f in [1024,2048):              WW[l*32+j] = sum_pr Ws[d,l*128+pr]*Wb[pr,j]
//   f in [2048,2560):              W_gate[d][f-2048]
// Block 512 == bias block (same folds applied to b_site / b_gate).
// Interleave map: f = 256q+4i+e  ->  l = 4*(i&7)+e,  r = (i>>3)+8q.
// ---------------------------------------------------------------------------
__global__ __launch_bounds__(256) void buildW_kernel(
    const float* __restrict__ Ws, const float* __restrict__ bs,
    const float* __restrict__ Wb, const float* __restrict__ Wg,
    const float* __restrict__ bg, float* __restrict__ Wcomb,
    float* __restrict__ biasC)
{
    const int tid = threadIdx.x;

    if (blockIdx.x == 512) {   // bias block
        for (int f = tid; f < NC_; f += 256) {
            float acc;
            if (f < 1024) {
                const int q = f >> 8, rem = f & 255, i = rem >> 2, e = rem & 3;
                const int l = 4 * (i & 7) + e, r = (i >> 3) + 8 * q;
                const float* p = bs + l * 128 + r;
                acc = p[0] + p[32] + p[64] + p[96];
            } else if (f < 2048) {
                const int g = f - 1024, l = g >> 5, j = g & 31;
                acc = 0.f;
                for (int pr = 0; pr < 128; ++pr)
                    acc = fmaf(bs[l * 128 + pr], Wb[pr * 32 + j], acc);
            } else {
                acc = bg[f - 2048];
            }
            biasC[f] = acc;
        }
        return;
    }

    __shared__ float wsrow[4096];
    __shared__ float wbs[4096];    // Wb[pr][j], pr*32+j

    const int d = blockIdx.x;
    #pragma unroll
    for (int i = 0; i < 16; ++i) {
        wsrow[i * 256 + tid] = Ws[(size_t)d * 4096 + i * 256 + tid];
        wbs[i * 256 + tid]   = Wb[i * 256 + tid];
    }
    __syncthreads();

    float* wrow = Wcomb + (size_t)d * NC_;

    // WA (interleaved): 4 cols/thread
    #pragma unroll
    for (int ii = 0; ii < 4; ++ii) {
        const int f = ii * 256 + tid;
        const int q = f >> 8, rem = f & 255, i = rem >> 2, e = rem & 3;
        const int l = 4 * (i & 7) + e, r = (i >> 3) + 8 * q;
        const float* p = wsrow + l * 128 + r;
        wrow[f] = p[0] + p[32] + p[64] + p[96];
    }
    // WW: 4 cols/thread, 128 FMA each
    #pragma unroll
    for (int ii = 0; ii < 4; ++ii) {
        const int g = ii * 256 + tid;
        const int l = g >> 5, j = g & 31;
        float acc = 0.f;
        #pragma unroll 8
        for (int pr = 0; pr < 128; ++pr)
            acc = fmaf(wsrow[l * 128 + pr], wbs[pr * 32 + j], acc);
        wrow[1024 + g] = acc;
    }
    // gate copy: 2 cols/thread
    #pragma unroll
    for (int ii = 0; ii < 2; ++ii) {
        const int c = ii * 256 + tid;
        wrow[2048 + c] = Wg[(size_t)d * 512 + c];
    }
}

// ---------------------------------------------------------------------------
// gemm1: C cols [0,1024) = AbarI.  64x64 tile, 256 threads, 4x4 acc/thread
// (round-0-proven body). Grid 16x64 = 1024 blocks -> ~4 blocks/CU so barrier
// and memory stalls overlap across co-resident blocks (the 128^2 version ran
// exactly 1 block/CU = 1 wave/SIMD with fully exposed stalls).
// ---------------------------------------------------------------------------
__global__ __launch_bounds__(256) void gemm_bias_kernel(
    const float* __restrict__ A, const float* __restrict__ Bm,
    const float* __restrict__ bias, float* __restrict__ C,
    int M, int N, int K)
{
    __shared__ float As[32][68];
    __shared__ float Bs[32][64];

    const int tid = threadIdx.x;
    const int tx = tid & 15;
    const int ty = tid >> 4;
    const int m0 = blockIdx.y * 64;
    const int n0 = blockIdx.x * 64;

    float c[4][4] = {};

    for (int k0 = 0; k0 < K; k0 += 32) {
        {
            const int o = tid * 8;
            const int m = o >> 5;
            const int k = o & 31;
            const float* ap = A + (size_t)(m0 + m) * K + k0 + k;
            const float4 a0 = *(const float4*)ap;
            const float4 a1 = *(const float4*)(ap + 4);
            As[k + 0][m] = a0.x; As[k + 1][m] = a0.y;
            As[k + 2][m] = a0.z; As[k + 3][m] = a0.w;
            As[k + 4][m] = a1.x; As[k + 5][m] = a1.y;
            As[k + 6][m] = a1.z; As[k + 7][m] = a1.w;
        }
        {
            const int o = tid * 8;
            const int k = o >> 6;
            const int n = o & 63;
            const float* bp = Bm + (size_t)(k0 + k) * N + n0 + n;
            *(float4*)&Bs[k][n]     = *(const float4*)bp;
            *(float4*)&Bs[k][n + 4] = *(const float4*)(bp + 4);
        }
        __syncthreads();

        #pragma unroll
        for (int kk = 0; kk < 32; ++kk) {
            const float4 av = *(const float4*)&As[kk][ty * 4];
            const float4 bv = *(const float4*)&Bs[kk][tx * 4];
            const float a[4] = {av.x, av.y, av.z, av.w};
            const float b[4] = {bv.x, bv.y, bv.z, bv.w};
            #pragma unroll
            for (int i = 0; i < 4; ++i)
                #pragma unroll
                for (int j = 0; j < 4; ++j)
                    c[i][j] = fmaf(a[i], b[j], c[i][j]);
        }
        __syncthreads();
    }

    const float4 bv = *(const float4*)&bias[n0 + tx * 4];
    #pragma unroll
    for (int i = 0; i < 4; ++i) {
        float4 outv;
        outv.x = c[i][0] + bv.x;
        outv.y = c[i][1] + bv.y;
        outv.z = c[i][2] + bv.z;
        outv.w = c[i][3] + bv.w;
        *(float4*)&C[(size_t)(m0 + ty * 4 + i) * N + n0 + tx * 4] = outv;
    }
}

// ---------------------------------------------------------------------------
// GEMM tile body for the fused kernel (128x128 tile, 8x8 acc/thread).
// ---------------------------------------------------------------------------
__device__ __forceinline__ void gemm_tile_body(
    const float* __restrict__ A, const float* __restrict__ Bm,
    const float* __restrict__ bias, float* __restrict__ C,
    int M, int N, int K, int m0, int n0,
    float (*As)[132], float (*Bs)[132])
{
    const int tid = threadIdx.x;
    const int tx = tid & 15;        // col group (n)
    const int ty = tid >> 4;        // row group (m)

    float acc[8][8] = {};

    for (int k0 = 0; k0 < K; k0 += 32) {
        // A tile: 128 rows x 32 k, write transposed As[k][m]
        #pragma unroll
        for (int p = 0; p < 4; ++p) {
            const int m = (tid >> 3) + 32 * p;
            const int k = (tid & 7) * 4;
            const float4 av = *(const float4*)(A + (size_t)(m0 + m) * K + k0 + k);
            As[k + 0][m] = av.x;
            As[k + 1][m] = av.y;
            As[k + 2][m] = av.z;
            As[k + 3][m] = av.w;
        }
        // B tile: 32 k x 128 n
        #pragma unroll
        for (int p = 0; p < 2; ++p) {
            const int k = (tid >> 4) + 16 * p;
            const int n = (tid & 15) * 8;
            const float* bp = Bm + (size_t)(k0 + k) * N + n0 + n;
            *(float4*)&Bs[k][n]     = *(const float4*)bp;
            *(float4*)&Bs[k][n + 4] = *(const float4*)(bp + 4);
        }
        __syncthreads();

        #pragma unroll
        for (int kk = 0; kk < 32; ++kk) {
            const float4 a0 = *(const float4*)&As[kk][ty * 8];
            const float4 a1 = *(const float4*)&As[kk][ty * 8 + 4];
            const float4 b0 = *(const float4*)&Bs[kk][tx * 8];
            const float4 b1 = *(const float4*)&Bs[kk][tx * 8 + 4];
            const float a[8] = {a0.x, a0.y, a0.z, a0.w, a1.x, a1.y, a1.z, a1.w};
            const float b[8] = {b0.x, b0.y, b0.z, b0.w, b1.x, b1.y, b1.z, b1.w};
            #pragma unroll
            for (int i = 0; i < 8; ++i)
                #pragma unroll
                for (int j = 0; j < 8; ++j)
                    acc[i][j] = fmaf(a[i], b[j], acc[i][j]);
        }
        __syncthreads();
    }

    const float4 bv0 = *(const float4*)&bias[n0 + tx * 8];
    const float4 bv1 = *(const float4*)&bias[n0 + tx * 8 + 4];
    #pragma unroll
    for (int i = 0; i < 8; ++i) {
        float* cp = C + (size_t)(m0 + ty * 8 + i) * N + n0 + tx * 8;
        float4 o0, o1;
        o0.x = acc[i][0] + bv0.x; o0.y = acc[i][1] + bv0.y;
        o0.z = acc[i][2] + bv0.z; o0.w = acc[i][3] + bv0.w;
        o1.x = acc[i][4] + bv1.x; o1.y = acc[i][5] + bv1.y;
        o1.z = acc[i][6] + bv1.z; o1.w = acc[i][7] + bv1.w;
        *(float4*)cp       = o0;
        *(float4*)(cp + 4) = o1;
    }
}

// ---------------------------------------------------------------------------
// cvec: c[bt][r] = sum_l u[l]*Abar[l][r], u = x[bt,0:32]. AbarI is the
// interleaved block at C[bt*NC_ + 0..1024). Same bpermute/octet machinery as
// the scan, one wave per bt (4 bt per 256-thread block).
// ---------------------------------------------------------------------------
__global__ __launch_bounds__(256) void cvec_kernel(
    const float* __restrict__ Cc, const float* __restrict__ x,
    float* __restrict__ cBuf)
{
    const int tid  = threadIdx.x;
    const int lane = tid & 63;
    const int bt   = blockIdx.x * 4 + (tid >> 6);

    const float* base = Cc + (size_t)bt * NC_ + 4 * lane;
    float4 a0 = *(const float4*)(base + 0);
    float4 a1 = *(const float4*)(base + 256);
    float4 a2 = *(const float4*)(base + 512);
    float4 a3 = *(const float4*)(base + 768);

    const float u = x[(size_t)bt * D_ + (lane & 31)];
    const int idx0 = 16 * (lane & 7);
    const float u0 = bpermute_f(idx0 + 0,  u);
    const float u1 = bpermute_f(idx0 + 4,  u);
    const float u2 = bpermute_f(idx0 + 8,  u);
    const float u3 = bpermute_f(idx0 + 12, u);

    float p0 = fmaf(u3, a0.w, fmaf(u2, a0.z, fmaf(u1, a0.y, u0 * a0.x)));
    float p1 = fmaf(u3, a1.w, fmaf(u2, a1.z, fmaf(u1, a1.y, u0 * a1.x)));
    float p2 = fmaf(u3, a2.w, fmaf(u2, a2.z, fmaf(u1, a2.y, u0 * a2.x)));
    float p3 = fmaf(u3, a3.w, fmaf(u2, a3.z, fmaf(u1, a3.y, u0 * a3.x)));

    p0 = octet_sum(p0); p1 = octet_sum(p1);
    p2 = octet_sum(p2); p3 = octet_sum(p3);

    if ((lane & 7) == 7) {          // top lane of octet k holds m[k+8q]
        const int k = lane >> 3;
        float* cp = cBuf + (size_t)bt * 32 + k;
        cp[0]  = p0;
        cp[8]  = p1;
        cp[16] = p2;
        cp[24] = p3;
    }
}

// ---------------------------------------------------------------------------
// FUSED: serial scan (blocks 0..3, tid<64) + GEMM part 2 (blocks 4..387,
// C columns [1024, 2560) = G + gate). The scan reads C cols [0,1024) and
// cBuf (both finalized by prior dispatches); the GEMM writes cols
// [1024,2560) -- fully disjoint, no inter-block dependency. During the
// scan's ~199 us (4 waves, 99% of the chip idle) the 384 GEMM blocks fill
// the idle CUs: ~90 us of GEMM cost hides under the scan (measured round 10:
// fused dispatch 231 us vs 199 us scan-solo).
//
// Scan recurrence (one wave per batch, verified round-0 machinery):
//   w_{t+1} = (w_t . Abar_t) * rsqrt(sum w_t^2) + c_t
// ---------------------------------------------------------------------------
__global__ __launch_bounds__(256) void fused_scan_gemm2_kernel(
    const float* __restrict__ x, const float* __restrict__ Wcomb,
    const float* __restrict__ biasC, float* __restrict__ Cc,
    const float* __restrict__ cBuf, float* __restrict__ wOut)
{
    __shared__ float As[32][132];
    __shared__ float Bs[32][132];

    if (blockIdx.x < 4) {
        // ------------------ scan path (threads 0..63 only) ------------------
        const int tid = threadIdx.x;
        if (tid >= 64) return;
        const int b = blockIdx.x;

        const float* At = Cc + (size_t)b * L_ * NC_ + 4 * tid;   // lane base
        const float* cb = cBuf + (size_t)b * L_ * 32 + (tid & 31);
        float*       wo = wOut + (size_t)b * L_ * 64 + tid;

        const int idx0 = 16 * (tid & 7);
        const int idxR = 32 * (tid & 7) + 28;    // octet TOP lane
        const bool selA = (tid >> 3) & 1;
        const bool selB = (tid >> 4) & 1;

        float4 areg[DPRE][4];
        float  creg[DPRE];

        #pragma unroll
        for (int j = 0; j < DPRE; ++j) {
            const float* ap = At + (size_t)j * NC_;
            #pragma unroll
            for (int q = 0; q < 4; ++q) areg[j][q] = *(const float4*)(ap + 256 * q);
            creg[j] = cb[j * 32];
        }

        float w = 0.f;   // w_0 = 0  (h_0 = 0)

        for (int t = 0; t < L_; t += DPRE) {
            #pragma unroll
            for (int j = 0; j < DPRE; ++j) {
                wo[(t + j) * 64] = w;

                float red = reduce32_to_lane31(w * w);

                const float wb0 = bpermute_f(idx0 + 0,  w);
                const float wb1 = bpermute_f(idx0 + 4,  w);
                const float wb2 = bpermute_f(idx0 + 8,  w);
                const float wb3 = bpermute_f(idx0 + 12, w);

                float p0, p1, p2, p3;
                {
                    const float4 a0 = areg[j][0], a1 = areg[j][1];
                    const float4 a2 = areg[j][2], a3 = areg[j][3];
                    p0 = fmaf(wb3, a0.w, fmaf(wb2, a0.z, fmaf(wb1, a0.y, wb0 * a0.x)));
                    p1 = fmaf(wb3, a1.w, fmaf(wb2, a1.z, fmaf(wb1, a1.y, wb0 * a1.x)));
                    p2 = fmaf(wb3, a2.w, fmaf(wb2, a2.z, fmaf(wb1, a2.y, wb0 * a2.x)));
                    p3 = fmaf(wb3, a3.w, fmaf(wb2, a3.z, fmaf(wb1, a3.y, wb0 * a3.x)));
                }

                p0 = octet_sum(p0);
                p1 = octet_sum(p1);
                p2 = octet_sum(p2);
                p3 = octet_sum(p3);

                const float m0 = bpermute_f(idxR, p0);
                const float m1 = bpermute_f(idxR, p1);
                const float m2 = bpermute_f(idxR, p2);
                const float m3 = bpermute_f(idxR, p3);
                const float t0 = selA ? m1 : m0;
                const float t1 = selA ? m3 : m2;
                const float m  = selB ? t1 : t0;

                const float n2 = readlane_f(red, 31);
                const float rn = rsqrtf(n2 + 1e-24f);
                w = fmaf(m, rn, creg[j]);

                int tn = t + j + DPRE;
                if (tn > L_ - 1) tn = L_ - 1;
                const float* ap = At + (size_t)tn * NC_;
                #pragma unroll
                for (int q = 0; q < 4; ++q) areg[j][q] = *(const float4*)(ap + 256 * q);
                creg[j] = cb[tn * 32];
            }
        }
        return;
    }

    // ------------------ GEMM part-2 path (cols 1024..2560) ------------------
    const int g  = blockIdx.x - 4;
    const int m0 = (g / 12) * 128;
    const int n0 = 1024 + (g % 12) * 128;
    gemm_tile_body(x, Wcomb, biasC, Cc, BT_, NC_, D_, m0, n0, As, Bs);
}

// ---------------------------------------------------------------------------
// Phase B: left = w/||w|| + u; y1[j] = sum_l left[l]*G[l*32+j] + bb[j],
// where G is C[bt*NC_ + 1024 ..2048).
// ---------------------------------------------------------------------------
__global__ __launch_bounds__(128) void phaseB_kernel(
    const float* __restrict__ Cc, const float* __restrict__ x,
    const float* __restrict__ wBuf, const float* __restrict__ bb,
    float* __restrict__ y1)
{
    __shared__ float lf[32];
    __shared__ float part[4][32];

    const int bt = blockIdx.x;
    const int tid = threadIdx.x;

    if (tid < 64) {
        const float wv = wBuf[(size_t)bt * 64 + tid];
        float red = reduce32_to_lane31(wv * wv);
        const float n2 = readlane_f(red, 31);
        const float rn = rsqrtf(n2 + 1e-24f);
        if (tid < 32)
            lf[tid] = fmaf(wv, rn, x[(size_t)bt * D_ + tid]);  // left = h + u
    }
    __syncthreads();

    const int j = tid & 31, q = tid >> 5;
    const float* Gp = Cc + (size_t)bt * NC_ + 1024;
    float p = 0.f;
    #pragma unroll
    for (int i = 0; i < 8; ++i)
        p = fmaf(lf[8 * q + i], Gp[(8 * q + i) * 32 + j], p);
    part[q][j] = p;
    __syncthreads();

    if (tid < 32)
        y1[bt * 32 + tid] = part[0][tid] + part[1][tid] + part[2][tid]
                          + part[3][tid] + bb[tid];
}

// ---------------------------------------------------------------------------
// Epilogue: y = y1 @ W_out + b_out; LayerNorm; gated residual with x.
// gate logits live in C[bt*NC_ + 2048 ..2560).
// ---------------------------------------------------------------------------
__global__ __launch_bounds__(256) void epilogue_kernel(
    const float* __restrict__ x, const float* __restrict__ y1buf,
    const float* __restrict__ Wout, const float* __restrict__ bout,
    const float* __restrict__ gamma, const float* __restrict__ beta,
    const float* __restrict__ Cc, float* __restrict__ out)
{
    __shared__ float ys[32];
    __shared__ float red1[4], red2[4];

    const int bt = blockIdx.x;
    const int tid = threadIdx.x;

    if (tid < 32) ys[tid] = y1buf[bt * 32 + tid];
    __syncthreads();

    float yv[2];
    #pragma unroll
    for (int q = 0; q < 2; ++q) {
        const int d = tid + q * 256;
        float acc = bout[d];
        #pragma unroll
        for (int j = 0; j < 32; ++j)
            acc = fmaf(ys[j], Wout[j * D_ + d], acc);
        yv[q] = acc;
    }

    float s1 = yv[0] + yv[1];
    float s2 = yv[0] * yv[0] + yv[1] * yv[1];
    #pragma unroll
    for (int m = 1; m <= 32; m <<= 1) {
        s1 += __shfl_xor(s1, m);
        s2 += __shfl_xor(s2, m);
    }
    const int wid = tid >> 6;
    if ((tid & 63) == 0) { red1[wid] = s1; red2[wid] = s2; }
    __syncthreads();
    const float S1 = red1[0] + red1[1] + red1[2] + red1[3];
    const float S2 = red2[0] + red2[1] + red2[2] + red2[3];
    const float mu  = S1 * (1.f / (float)D_);
    const float var = S2 * (1.f / (float)D_) - mu * mu;
    const float rstd = rsqrtf(var + 1e-6f);

    #pragma unroll
    for (int q = 0; q < 2; ++q) {
        const int d = tid + q * 256;
        const size_t gi = (size_t)bt * D_ + d;
        const float yn = (yv[q] - mu) * rstd * gamma[d] + beta[d];
        const float z = Cc[(size_t)bt * NC_ + 2048 + d];
        const float g = 1.f / (1.f + expf(-z));
        const float xv = x[gi];
        out[gi] = g * yn + (1.f - g) * xv;
    }
}

// ---------------------------------------------------------------------------
extern "C" void kernel_launch(void* const* d_in, const int* in_sizes, int n_in,
                              void* d_out, int out_size, void* d_ws, size_t ws_size,
                              hipStream_t stream)
{
    const float* x        = (const float*)d_in[0];
    const float* W_site   = (const float*)d_in[1];
    const float* b_site   = (const float*)d_in[2];
    const float* W_bridge = (const float*)d_in[3];
    const float* b_bridge = (const float*)d_in[4];
    const float* W_out    = (const float*)d_in[5];
    const float* b_out    = (const float*)d_in[6];
    const float* gamma    = (const float*)d_in[7];
    const float* beta     = (const float*)d_in[8];
    const float* W_gate   = (const float*)d_in[9];
    const float* b_gate   = (const float*)d_in[10];
    float* out = (float*)d_out;

    float* ws = (float*)d_ws;
    float* Wcomb = ws;                            //   512*2560 = 1,310,720 f
    float* biasC = Wcomb + (size_t)512 * NC_;     //        2,560 f
    float* Cc    = biasC + NC_;                   // 4096*2560 = 10,485,760 f (42 MB)
    float* cBuf  = Cc    + (size_t)BT_ * NC_;     //      131,072 f
    float* wBuf  = cBuf  + (size_t)BT_ * 32;      //      262,144 f
    float* y1    = wBuf  + (size_t)BT_ * 64;      //      131,072 f

    // 0. fold weights: [WA_perm | WW | W_gate] + fused bias
    buildW_kernel<<<dim3(513), dim3(256), 0, stream>>>(
        W_site, b_site, W_bridge, W_gate, b_gate, Wcomb, biasC);

    // 1. GEMM part 1: C cols [0,1024) = AbarI   [4096 x 1024, K=512]
    //    64x64 tiles -> 1024 blocks (~4/CU) for latency hiding.
    gemm_bias_kernel<<<dim3(16, 64), dim3(256), 0, stream>>>(
        x, Wcomb, biasC, Cc, BT_, NC_, D_);

    // 2. c vectors: c = u . Abar  (fully parallel)
    cvec_kernel<<<dim3(BT_ / 4), dim3(256), 0, stream>>>(Cc, x, cBuf);

    // 3. FUSED: scan (blocks 0..3) + GEMM part 2 (cols 1024..2560, blocks
    //    4..387) -- part 2 hides under the scan on idle CUs.
    fused_scan_gemm2_kernel<<<dim3(4 + 12 * (BT_ / 128)), dim3(256), 0, stream>>>(
        x, Wcomb, biasC, Cc, cBuf, wBuf);

    // 4. phase B: y1 = left . G + bb
    phaseB_kernel<<<dim3(BT_), dim3(128), 0, stream>>>(
        Cc, x, wBuf, b_bridge, y1);

    // 5. epilogue: out-proj + LN + gated residual (gate from C)
    epilogue_kernel<<<dim3(BT_), dim3(256), 0, stream>>>(
        x, y1, W_out, b_out, gamma, beta, Cc, out);
}

// Round 13
// 386.415 us; speedup vs baseline: 1.0269x; 1.0081x over previous
//
#include <hip/hip_runtime.h>
#include <math.h>

// Problem dims (fixed by reference)
#define B_   4
#define L_   1024
#define D_   512
#define CHI_ 32
#define S_   4
#define BT_  (B_ * L_)          // 4096 rows
#define NC_  2560               // fused GEMM width: 1024 AbarI | 1024 G | 512 gate
#define DPRE 8                  // scan prefetch distance (register ring)

// ---------------------------------------------------------------------------
// Cross-lane helpers
// ---------------------------------------------------------------------------
__device__ __forceinline__ float readlane_f(float v, int l) {
    return __int_as_float(__builtin_amdgcn_readlane(__float_as_int(v), l));
}

__device__ __forceinline__ float bpermute_f(int byte_idx, float v) {
    return __int_as_float(__builtin_amdgcn_ds_bpermute(byte_idx, __float_as_int(v)));
}

template <int CTRL>
__device__ __forceinline__ float dpp_add(float x) {
    int y = __builtin_amdgcn_update_dpp(0, __float_as_int(x), CTRL, 0xf, 0xf, true);
    return x + __int_as_float(y);
}

// Sum of lanes 0..31, valid in lane 31 (row_shr moves toward HIGHER lanes).
__device__ __forceinline__ float reduce32_to_lane31(float x) {
    x = dpp_add<0x111>(x);
    x = dpp_add<0x112>(x);
    x = dpp_add<0x114>(x);
    x = dpp_add<0x118>(x);
    x = dpp_add<0x142>(x);  // row_bcast15 -> lane31
    return x;
}

// Octet sum; complete sum lands in the TOP lane of each octet ((lane&7)==7).
__device__ __forceinline__ float octet_sum(float x) {
    x = dpp_add<0x111>(x);
    x = dpp_add<0x112>(x);
    x = dpp_add<0x114>(x);
    return x;
}

// ---------------------------------------------------------------------------
// buildW_A: WA fold (scan-interleaved Abar columns, cols [0,1024)) + ALL
// biases. The WW fold + gate copy (cols [1024,2560)) moved into the gemm1
// dispatch (buildW_B blocks) -- they are only needed by the fused gemm2.
// Interleave map: f = 256q+4i+e  ->  l = 4*(i&7)+e,  r = (i>>3)+8q.
// ---------------------------------------------------------------------------
__global__ __launch_bounds__(256) void buildWA_kernel(
    const float* __restrict__ Ws, const float* __restrict__ bs,
    const float* __restrict__ Wb, const float* __restrict__ bg,
    float* __restrict__ Wcomb, float* __restrict__ biasC)
{
    const int tid = threadIdx.x;

    if (blockIdx.x == 512) {   // bias block
        for (int f = tid; f < NC_; f += 256) {
            float acc;
            if (f < 1024) {
                const int q = f >> 8, rem = f & 255, i = rem >> 2, e = rem & 3;
                const int l = 4 * (i & 7) + e, r = (i >> 3) + 8 * q;
                const float* p = bs + l * 128 + r;
                acc = p[0] + p[32] + p[64] + p[96];
            } else if (f < 2048) {
                const int g = f - 1024, l = g >> 5, j = g & 31;
                acc = 0.f;
                for (int pr = 0; pr < 128; ++pr)
                    acc = fmaf(bs[l * 128 + pr], Wb[pr * 32 + j], acc);
            } else {
                acc = bg[f - 2048];
            }
            biasC[f] = acc;
        }
        return;
    }

    __shared__ float wsrow[4096];

    const int d = blockIdx.x;
    #pragma unroll
    for (int i = 0; i < 16; ++i)
        wsrow[i * 256 + tid] = Ws[(size_t)d * 4096 + i * 256 + tid];
    __syncthreads();

    float* wrow = Wcomb + (size_t)d * NC_;

    // WA (interleaved): 4 cols/thread
    #pragma unroll
    for (int ii = 0; ii < 4; ++ii) {
        const int f = ii * 256 + tid;
        const int q = f >> 8, rem = f & 255, i = rem >> 2, e = rem & 3;
        const int l = 4 * (i & 7) + e, r = (i >> 3) + 8 * q;
        const float* p = wsrow + l * 128 + r;
        wrow[f] = p[0] + p[32] + p[64] + p[96];
    }
}

// ---------------------------------------------------------------------------
// gemm1 + buildW_B, one dispatch (disjoint Wcomb regions: gemm1 READS cols
// [0,1024), buildW_B WRITES cols [1024,2560) -- no inter-block dependency).
//   blocks 0..511:    buildW_B: WW[l*32+j] = sum_pr Ws[d,l*128+pr]*Wb[pr,j]
//                     for cols [1024,2048), gate copy for [2048,2560).
//   blocks 512..1535: gemm1 64x64 tiles of C = x @ Wcomb + biasC,
//                     cols [0,1024) (AbarI block; round-0-proven body).
// Shared-mem union (32 KB): gemm path As[32][68]+Bs[32][64]; buildW_B path
// wsrow[4096]+wbs[4096].
// ---------------------------------------------------------------------------
__global__ __launch_bounds__(256) void gemm1_buildWB_kernel(
    const float* __restrict__ x, const float* __restrict__ Ws,
    const float* __restrict__ Wb, const float* __restrict__ Wg,
    float* Wcomb, const float* __restrict__ biasC, float* __restrict__ C)
{
    __shared__ __align__(16) float smem[8192];

    const int tid = threadIdx.x;

    if (blockIdx.x < 512) {
        // ---------------- buildW_B: WW fold + gate copy ----------------
        float* wsrow = smem;          // Ws row d   (4096)
        float* wbs   = smem + 4096;   // Wb[pr][j]  (4096)

        const int d = blockIdx.x;
        #pragma unroll
        for (int i = 0; i < 16; ++i) {
            wsrow[i * 256 + tid] = Ws[(size_t)d * 4096 + i * 256 + tid];
            wbs[i * 256 + tid]   = Wb[i * 256 + tid];
        }
        __syncthreads();

        float* wrow = Wcomb + (size_t)d * NC_;

        // WW: 4 cols/thread, 128 FMA each
        #pragma unroll
        for (int ii = 0; ii < 4; ++ii) {
            const int g = ii * 256 + tid;
            const int l = g >> 5, j = g & 31;
            float acc = 0.f;
            #pragma unroll 8
            for (int pr = 0; pr < 128; ++pr)
                acc = fmaf(wsrow[l * 128 + pr], wbs[pr * 32 + j], acc);
            wrow[1024 + g] = acc;
        }
        // gate copy: 2 cols/thread
        #pragma unroll
        for (int ii = 0; ii < 2; ++ii) {
            const int c = ii * 256 + tid;
            wrow[2048 + c] = Wg[(size_t)d * 512 + c];
        }
        return;
    }

    // ---------------- gemm1: 64x64 tile, 4x4 acc/thread ----------------
    float (*As)[68] = (float(*)[68])smem;             // 32*68 = 2176
    float (*Bs)[64] = (float(*)[64])(smem + 32 * 68); // 32*64 = 2048

    const int g  = blockIdx.x - 512;
    const int m0 = (g >> 4) * 64;          // 64 row-tiles
    const int n0 = (g & 15) * 64;          // 16 col-tiles (cols 0..1024)
    const int tx = tid & 15;
    const int ty = tid >> 4;
    const int K = D_, N = NC_;

    float c[4][4] = {};

    for (int k0 = 0; k0 < K; k0 += 32) {
        {
            const int o = tid * 8;
            const int m = o >> 5;
            const int k = o & 31;
            const float* ap = x + (size_t)(m0 + m) * K + k0 + k;
            const float4 a0 = *(const float4*)ap;
            const float4 a1 = *(const float4*)(ap + 4);
            As[k + 0][m] = a0.x; As[k + 1][m] = a0.y;
            As[k + 2][m] = a0.z; As[k + 3][m] = a0.w;
            As[k + 4][m] = a1.x; As[k + 5][m] = a1.y;
            As[k + 6][m] = a1.z; As[k + 7][m] = a1.w;
        }
        {
            const int o = tid * 8;
            const int k = o >> 6;
            const int n = o & 63;
            const float* bp = Wcomb + (size_t)(k0 + k) * N + n0 + n;
            *(float4*)&Bs[k][n]     = *(const float4*)bp;
            *(float4*)&Bs[k][n + 4] = *(const float4*)(bp + 4);
        }
        __syncthreads();

        #pragma unroll
        for (int kk = 0; kk < 32; ++kk) {
            const float4 av = *(const float4*)&As[kk][ty * 4];
            const float4 bv = *(const float4*)&Bs[kk][tx * 4];
            const float a[4] = {av.x, av.y, av.z, av.w};
            const float b[4] = {bv.x, bv.y, bv.z, bv.w};
            #pragma unroll
            for (int i = 0; i < 4; ++i)
                #pragma unroll
                for (int j = 0; j < 4; ++j)
                    c[i][j] = fmaf(a[i], b[j], c[i][j]);
        }
        __syncthreads();
    }

    const float4 bv = *(const float4*)&biasC[n0 + tx * 4];
    #pragma unroll
    for (int i = 0; i < 4; ++i) {
        float4 outv;
        outv.x = c[i][0] + bv.x;
        outv.y = c[i][1] + bv.y;
        outv.z = c[i][2] + bv.z;
        outv.w = c[i][3] + bv.w;
        *(float4*)&C[(size_t)(m0 + ty * 4 + i) * N + n0 + tx * 4] = outv;
    }
}

// ---------------------------------------------------------------------------
// GEMM tile body for the fused kernel (128x128 tile, 8x8 acc/thread).
// ---------------------------------------------------------------------------
__device__ __forceinline__ void gemm_tile_body(
    const float* __restrict__ A, const float* __restrict__ Bm,
    const float* __restrict__ bias, float* __restrict__ C,
    int M, int N, int K, int m0, int n0,
    float (*As)[132], float (*Bs)[132])
{
    const int tid = threadIdx.x;
    const int tx = tid & 15;        // col group (n)
    const int ty = tid >> 4;        // row group (m)

    float acc[8][8] = {};

    for (int k0 = 0; k0 < K; k0 += 32) {
        // A tile: 128 rows x 32 k, write transposed As[k][m]
        #pragma unroll
        for (int p = 0; p < 4; ++p) {
            const int m = (tid >> 3) + 32 * p;
            const int k = (tid & 7) * 4;
            const float4 av = *(const float4*)(A + (size_t)(m0 + m) * K + k0 + k);
            As[k + 0][m] = av.x;
            As[k + 1][m] = av.y;
            As[k + 2][m] = av.z;
            As[k + 3][m] = av.w;
        }
        // B tile: 32 k x 128 n
        #pragma unroll
        for (int p = 0; p < 2; ++p) {
            const int k = (tid >> 4) + 16 * p;
            const int n = (tid & 15) * 8;
            const float* bp = Bm + (size_t)(k0 + k) * N + n0 + n;
            *(float4*)&Bs[k][n]     = *(const float4*)bp;
            *(float4*)&Bs[k][n + 4] = *(const float4*)(bp + 4);
        }
        __syncthreads();

        #pragma unroll
        for (int kk = 0; kk < 32; ++kk) {
            const float4 a0 = *(const float4*)&As[kk][ty * 8];
            const float4 a1 = *(const float4*)&As[kk][ty * 8 + 4];
            const float4 b0 = *(const float4*)&Bs[kk][tx * 8];
            const float4 b1 = *(const float4*)&Bs[kk][tx * 8 + 4];
            const float a[8] = {a0.x, a0.y, a0.z, a0.w, a1.x, a1.y, a1.z, a1.w};
            const float b[8] = {b0.x, b0.y, b0.z, b0.w, b1.x, b1.y, b1.z, b1.w};
            #pragma unroll
            for (int i = 0; i < 8; ++i)
                #pragma unroll
                for (int j = 0; j < 8; ++j)
                    acc[i][j] = fmaf(a[i], b[j], acc[i][j]);
        }
        __syncthreads();
    }

    const float4 bv0 = *(const float4*)&bias[n0 + tx * 8];
    const float4 bv1 = *(const float4*)&bias[n0 + tx * 8 + 4];
    #pragma unroll
    for (int i = 0; i < 8; ++i) {
        float* cp = C + (size_t)(m0 + ty * 8 + i) * N + n0 + tx * 8;
        float4 o0, o1;
        o0.x = acc[i][0] + bv0.x; o0.y = acc[i][1] + bv0.y;
        o0.z = acc[i][2] + bv0.z; o0.w = acc[i][3] + bv0.w;
        o1.x = acc[i][4] + bv1.x; o1.y = acc[i][5] + bv1.y;
        o1.z = acc[i][6] + bv1.z; o1.w = acc[i][7] + bv1.w;
        *(float4*)cp       = o0;
        *(float4*)(cp + 4) = o1;
    }
}

// ---------------------------------------------------------------------------
// cvec: c[bt][r] = sum_l u[l]*Abar[l][r], u = x[bt,0:32]. AbarI is the
// interleaved block at C[bt*NC_ + 0..1024). One wave per bt.
// ---------------------------------------------------------------------------
__global__ __launch_bounds__(256) void cvec_kernel(
    const float* __restrict__ Cc, const float* __restrict__ x,
    float* __restrict__ cBuf)
{
    const int tid  = threadIdx.x;
    const int lane = tid & 63;
    const int bt   = blockIdx.x * 4 + (tid >> 6);

    const float* base = Cc + (size_t)bt * NC_ + 4 * lane;
    float4 a0 = *(const float4*)(base + 0);
    float4 a1 = *(const float4*)(base + 256);
    float4 a2 = *(const float4*)(base + 512);
    float4 a3 = *(const float4*)(base + 768);

    const float u = x[(size_t)bt * D_ + (lane & 31)];
    const int idx0 = 16 * (lane & 7);
    const float u0 = bpermute_f(idx0 + 0,  u);
    const float u1 = bpermute_f(idx0 + 4,  u);
    const float u2 = bpermute_f(idx0 + 8,  u);
    const float u3 = bpermute_f(idx0 + 12, u);

    float p0 = fmaf(u3, a0.w, fmaf(u2, a0.z, fmaf(u1, a0.y, u0 * a0.x)));
    float p1 = fmaf(u3, a1.w, fmaf(u2, a1.z, fmaf(u1, a1.y, u0 * a1.x)));
    float p2 = fmaf(u3, a2.w, fmaf(u2, a2.z, fmaf(u1, a2.y, u0 * a2.x)));
    float p3 = fmaf(u3, a3.w, fmaf(u2, a3.z, fmaf(u1, a3.y, u0 * a3.x)));

    p0 = octet_sum(p0); p1 = octet_sum(p1);
    p2 = octet_sum(p2); p3 = octet_sum(p3);

    if ((lane & 7) == 7) {          // top lane of octet k holds m[k+8q]
        const int k = lane >> 3;
        float* cp = cBuf + (size_t)bt * 32 + k;
        cp[0]  = p0;
        cp[8]  = p1;
        cp[16] = p2;
        cp[24] = p3;
    }
}

// ---------------------------------------------------------------------------
// FUSED: serial scan (blocks 0..3, tid<64) + GEMM part 2 (blocks 4..387,
// C columns [1024, 2560) = G + gate). The scan reads C cols [0,1024) and
// cBuf (both finalized by prior dispatches); the GEMM writes cols
// [1024,2560) -- fully disjoint, no inter-block dependency. During the
// scan's ~199 us (4 waves) the 384 GEMM blocks fill the idle CUs
// (measured round 10/12: fused dispatch 222-231 us vs 199 us scan-solo).
//
// Scan recurrence (one wave per batch, verified round-0 machinery):
//   w_{t+1} = (w_t . Abar_t) * rsqrt(sum w_t^2) + c_t
// ---------------------------------------------------------------------------
__global__ __launch_bounds__(256) void fused_scan_gemm2_kernel(
    const float* __restrict__ x, const float* __restrict__ Wcomb,
    const float* __restrict__ biasC, float* __restrict__ Cc,
    const float* __restrict__ cBuf, float* __restrict__ wOut)
{
    __shared__ float As[32][132];
    __shared__ float Bs[32][132];

    if (blockIdx.x < 4) {
        // ------------------ scan path (threads 0..63 only) ------------------
        const int tid = threadIdx.x;
        if (tid >= 64) return;
        const int b = blockIdx.x;

        const float* At = Cc + (size_t)b * L_ * NC_ + 4 * tid;   // lane base
        const float* cb = cBuf + (size_t)b * L_ * 32 + (tid & 31);
        float*       wo = wOut + (size_t)b * L_ * 64 + tid;

        const int idx0 = 16 * (tid & 7);
        const int idxR = 32 * (tid & 7) + 28;    // octet TOP lane
        const bool selA = (tid >> 3) & 1;
        const bool selB = (tid >> 4) & 1;

        float4 areg[DPRE][4];
        float  creg[DPRE];

        #pragma unroll
        for (int j = 0; j < DPRE; ++j) {
            const float* ap = At + (size_t)j * NC_;
            #pragma unroll
            for (int q = 0; q < 4; ++q) areg[j][q] = *(const float4*)(ap + 256 * q);
            creg[j] = cb[j * 32];
        }

        float w = 0.f;   // w_0 = 0  (h_0 = 0)

        for (int t = 0; t < L_; t += DPRE) {
            #pragma unroll
            for (int j = 0; j < DPRE; ++j) {
                wo[(t + j) * 64] = w;

                float red = reduce32_to_lane31(w * w);

                const float wb0 = bpermute_f(idx0 + 0,  w);
                const float wb1 = bpermute_f(idx0 + 4,  w);
                const float wb2 = bpermute_f(idx0 + 8,  w);
                const float wb3 = bpermute_f(idx0 + 12, w);

                float p0, p1, p2, p3;
                {
                    const float4 a0 = areg[j][0], a1 = areg[j][1];
                    const float4 a2 = areg[j][2], a3 = areg[j][3];
                    p0 = fmaf(wb3, a0.w, fmaf(wb2, a0.z, fmaf(wb1, a0.y, wb0 * a0.x)));
                    p1 = fmaf(wb3, a1.w, fmaf(wb2, a1.z, fmaf(wb1, a1.y, wb0 * a1.x)));
                    p2 = fmaf(wb3, a2.w, fmaf(wb2, a2.z, fmaf(wb1, a2.y, wb0 * a2.x)));
                    p3 = fmaf(wb3, a3.w, fmaf(wb2, a3.z, fmaf(wb1, a3.y, wb0 * a3.x)));
                }

                p0 = octet_sum(p0);
                p1 = octet_sum(p1);
                p2 = octet_sum(p2);
                p3 = octet_sum(p3);

                const float m0 = bpermute_f(idxR, p0);
                const float m1 = bpermute_f(idxR, p1);
                const float m2 = bpermute_f(idxR, p2);
                const float m3 = bpermute_f(idxR, p3);
                const float t0 = selA ? m1 : m0;
                const float t1 = selA ? m3 : m2;
                const float m  = selB ? t1 : t0;

                const float n2 = readlane_f(red, 31);
                const float rn = rsqrtf(n2 + 1e-24f);
                w = fmaf(m, rn, creg[j]);

                int tn = t + j + DPRE;
                if (tn > L_ - 1) tn = L_ - 1;
                const float* ap = At + (size_t)tn * NC_;
                #pragma unroll
                for (int q = 0; q < 4; ++q) areg[j][q] = *(const float4*)(ap + 256 * q);
                creg[j] = cb[tn * 32];
            }
        }
        return;
    }

    // ------------------ GEMM part-2 path (cols 1024..2560) ------------------
    const int g  = blockIdx.x - 4;
    const int m0 = (g / 12) * 128;
    const int n0 = 1024 + (g % 12) * 128;
    gemm_tile_body(x, Wcomb, biasC, Cc, BT_, NC_, D_, m0, n0, As, Bs);
}

// ---------------------------------------------------------------------------
// FUSED phaseB + epilogue (one block per bt, 256 threads; passed round 11):
//   lf = w/||w|| + u                       (threads 0..63)
//   y1[j] = sum_l lf[l]*G[l*32+j] + bb[j]  (8 groups x 32, G in C cols 1024+)
//   y = y1 @ W_out + b_out; LayerNorm; gated residual (gate from C cols 2048+)
// ---------------------------------------------------------------------------
__global__ __launch_bounds__(256) void phaseB_epilogue_kernel(
    const float* __restrict__ Cc, const float* __restrict__ x,
    const float* __restrict__ wBuf, const float* __restrict__ bb,
    const float* __restrict__ Wout, const float* __restrict__ bout,
    const float* __restrict__ gamma, const float* __restrict__ beta,
    float* __restrict__ out)
{
    __shared__ float lf[32];
    __shared__ float part[8][32];
    __shared__ float ys[32];
    __shared__ float red1[4], red2[4];

    const int bt = blockIdx.x;
    const int tid = threadIdx.x;

    if (tid < 64) {
        const float wv = wBuf[(size_t)bt * 64 + tid];
        float red = reduce32_to_lane31(wv * wv);
        const float n2 = readlane_f(red, 31);
        const float rn = rsqrtf(n2 + 1e-24f);
        if (tid < 32)
            lf[tid] = fmaf(wv, rn, x[(size_t)bt * D_ + tid]);  // left = h + u
    }
    __syncthreads();

    {
        const int j = tid & 31, q = tid >> 5;   // q in 0..7, 4 l's each
        const float* Gp = Cc + (size_t)bt * NC_ + 1024;
        float p = 0.f;
        #pragma unroll
        for (int i = 0; i < 4; ++i)
            p = fmaf(lf[4 * q + i], Gp[(4 * q + i) * 32 + j], p);
        part[q][j] = p;
    }
    __syncthreads();

    if (tid < 32) {
        float s = bb[tid];
        #pragma unroll
        for (int q = 0; q < 8; ++q) s += part[q][tid];
        ys[tid] = s;
    }
    __syncthreads();

    float yv[2];
    #pragma unroll
    for (int q = 0; q < 2; ++q) {
        const int d = tid + q * 256;
        float acc = bout[d];
        #pragma unroll
        for (int j = 0; j < 32; ++j)
            acc = fmaf(ys[j], Wout[j * D_ + d], acc);
        yv[q] = acc;
    }

    float s1 = yv[0] + yv[1];
    float s2 = yv[0] * yv[0] + yv[1] * yv[1];
    #pragma unroll
    for (int m = 1; m <= 32; m <<= 1) {
        s1 += __shfl_xor(s1, m);
        s2 += __shfl_xor(s2, m);
    }
    const int wid = tid >> 6;
    if ((tid & 63) == 0) { red1[wid] = s1; red2[wid] = s2; }
    __syncthreads();
    const float S1 = red1[0] + red1[1] + red1[2] + red1[3];
    const float S2 = red2[0] + red2[1] + red2[2] + red2[3];
    const float mu  = S1 * (1.f / (float)D_);
    const float var = S2 * (1.f / (float)D_) - mu * mu;
    const float rstd = rsqrtf(var + 1e-6f);

    #pragma unroll
    for (int q = 0; q < 2; ++q) {
        const int d = tid + q * 256;
        const size_t gi = (size_t)bt * D_ + d;
        const float yn = (yv[q] - mu) * rstd * gamma[d] + beta[d];
        const float z = Cc[(size_t)bt * NC_ + 2048 + d];
        const float g = 1.f / (1.f + expf(-z));
        const float xv = x[gi];
        out[gi] = g * yn + (1.f - g) * xv;
    }
}

// ---------------------------------------------------------------------------
extern "C" void kernel_launch(void* const* d_in, const int* in_sizes, int n_in,
                              void* d_out, int out_size, void* d_ws, size_t ws_size,
                              hipStream_t stream)
{
    const float* x        = (const float*)d_in[0];
    const float* W_site   = (const float*)d_in[1];
    const float* b_site   = (const float*)d_in[2];
    const float* W_bridge = (const float*)d_in[3];
    const float* b_bridge = (const float*)d_in[4];
    const float* W_out    = (const float*)d_in[5];
    const float* b_out    = (const float*)d_in[6];
    const float* gamma    = (const float*)d_in[7];
    const float* beta     = (const float*)d_in[8];
    const float* W_gate   = (const float*)d_in[9];
    const float* b_gate   = (const float*)d_in[10];
    float* out = (float*)d_out;

    float* ws = (float*)d_ws;
    float* Wcomb = ws;                            //   512*2560 = 1,310,720 f
    float* biasC = Wcomb + (size_t)512 * NC_;     //        2,560 f
    float* Cc    = biasC + NC_;                   // 4096*2560 = 10,485,760 f (42 MB)
    float* cBuf  = Cc    + (size_t)BT_ * NC_;     //      131,072 f
    float* wBuf  = cBuf  + (size_t)BT_ * 32;      //      262,144 f

    // 0. buildW_A: WA fold (cols 0..1024) + all biases
    buildWA_kernel<<<dim3(513), dim3(256), 0, stream>>>(
        W_site, b_site, W_bridge, b_gate, Wcomb, biasC);

    // 1. gemm1 (C cols [0,1024) = AbarI, 64^2 tiles) + buildW_B (WW fold +
    //    gate copy, Wcomb cols [1024,2560)) in one dispatch -- disjoint work.
    gemm1_buildWB_kernel<<<dim3(512 + 1024), dim3(256), 0, stream>>>(
        x, W_site, W_bridge, W_gate, Wcomb, biasC, Cc);

    // 2. c vectors: c = u . Abar  (fully parallel)
    cvec_kernel<<<dim3(BT_ / 4), dim3(256), 0, stream>>>(Cc, x, cBuf);

    // 3. FUSED: scan (blocks 0..3) + GEMM part 2 (cols 1024..2560, blocks
    //    4..387) -- part 2 hides under the scan on idle CUs.
    fused_scan_gemm2_kernel<<<dim3(4 + 12 * (BT_ / 128)), dim3(256), 0, stream>>>(
        x, Wcomb, biasC, Cc, cBuf, wBuf);

    // 4. FUSED phaseB + epilogue
    phaseB_epilogue_kernel<<<dim3(BT_), dim3(256), 0, stream>>>(
        Cc, x, wBuf, b_bridge, W_out, b_out, gamma, beta, out);
}

// Round 14
// 382.777 us; speedup vs baseline: 1.0366x; 1.0095x over previous
//
#include <hip/hip_runtime.h>
#include <math.h>

// Problem dims (fixed by reference)
#define B_   4
#define L_   1024
#define D_   512
#define CHI_ 32
#define S_   4
#define BT_  (B_ * L_)          // 4096 rows
#define NC_  2560               // fused GEMM width: 1024 AbarI | 1024 G | 512 gate
#define DPRE 8                  // scan prefetch distance (register ring)

// ---------------------------------------------------------------------------
// Cross-lane helpers
// ---------------------------------------------------------------------------
__device__ __forceinline__ float readlane_f(float v, int l) {
    return __int_as_float(__builtin_amdgcn_readlane(__float_as_int(v), l));
}

__device__ __forceinline__ float bpermute_f(int byte_idx, float v) {
    return __int_as_float(__builtin_amdgcn_ds_bpermute(byte_idx, __float_as_int(v)));
}

template <int CTRL>
__device__ __forceinline__ float dpp_add(float x) {
    int y = __builtin_amdgcn_update_dpp(0, __float_as_int(x), CTRL, 0xf, 0xf, true);
    return x + __int_as_float(y);
}

// Sum of lanes 0..31, valid in lane 31 (row_shr moves toward HIGHER lanes).
__device__ __forceinline__ float reduce32_to_lane31(float x) {
    x = dpp_add<0x111>(x);
    x = dpp_add<0x112>(x);
    x = dpp_add<0x114>(x);
    x = dpp_add<0x118>(x);
    x = dpp_add<0x142>(x);  // row_bcast15 -> lane31
    return x;
}

// Octet sum; complete sum lands in the TOP lane of each octet ((lane&7)==7).
__device__ __forceinline__ float octet_sum(float x) {
    x = dpp_add<0x111>(x);
    x = dpp_add<0x112>(x);
    x = dpp_add<0x114>(x);
    return x;
}

// ---------------------------------------------------------------------------
// buildW_A: WA fold (scan-interleaved Abar columns, cols [0,1024)) + ALL
// biases. The WW fold + gate copy (cols [1024,2560)) live in the gemm1
// dispatch (buildW_B blocks) -- they are only needed by the fused gemm2.
// Interleave map: f = 256q+4i+e  ->  l = 4*(i&7)+e,  r = (i>>3)+8q.
// ---------------------------------------------------------------------------
__global__ __launch_bounds__(256) void buildWA_kernel(
    const float* __restrict__ Ws, const float* __restrict__ bs,
    const float* __restrict__ Wb, const float* __restrict__ bg,
    float* __restrict__ Wcomb, float* __restrict__ biasC)
{
    const int tid = threadIdx.x;

    if (blockIdx.x == 512) {   // bias block
        for (int f = tid; f < NC_; f += 256) {
            float acc;
            if (f < 1024) {
                const int q = f >> 8, rem = f & 255, i = rem >> 2, e = rem & 3;
                const int l = 4 * (i & 7) + e, r = (i >> 3) + 8 * q;
                const float* p = bs + l * 128 + r;
                acc = p[0] + p[32] + p[64] + p[96];
            } else if (f < 2048) {
                const int g = f - 1024, l = g >> 5, j = g & 31;
                acc = 0.f;
                for (int pr = 0; pr < 128; ++pr)
                    acc = fmaf(bs[l * 128 + pr], Wb[pr * 32 + j], acc);
            } else {
                acc = bg[f - 2048];
            }
            biasC[f] = acc;
        }
        return;
    }

    __shared__ float wsrow[4096];

    const int d = blockIdx.x;
    #pragma unroll
    for (int i = 0; i < 16; ++i)
        wsrow[i * 256 + tid] = Ws[(size_t)d * 4096 + i * 256 + tid];
    __syncthreads();

    float* wrow = Wcomb + (size_t)d * NC_;

    // WA (interleaved): 4 cols/thread
    #pragma unroll
    for (int ii = 0; ii < 4; ++ii) {
        const int f = ii * 256 + tid;
        const int q = f >> 8, rem = f & 255, i = rem >> 2, e = rem & 3;
        const int l = 4 * (i & 7) + e, r = (i >> 3) + 8 * q;
        const float* p = wsrow + l * 128 + r;
        wrow[f] = p[0] + p[32] + p[64] + p[96];
    }
}

// ---------------------------------------------------------------------------
// gemm1 + buildW_B, one dispatch (disjoint Wcomb regions: gemm1 READS cols
// [0,1024), buildW_B WRITES cols [1024,2560) -- no inter-block dependency).
//   blocks 0..511:    buildW_B: WW[l*32+j] = sum_pr Ws[d,l*128+pr]*Wb[pr,j]
//                     for cols [1024,2048), gate copy for [2048,2560).
//   blocks 512..1535: gemm1 64x64 tiles of C = x @ Wcomb + biasC,
//                     cols [0,1024) (AbarI block; round-0-proven body).
// Shared-mem union (32 KB): gemm path As[32][68]+Bs[32][64]; buildW_B path
// wsrow[4096]+wbs[4096].
// ---------------------------------------------------------------------------
__global__ __launch_bounds__(256) void gemm1_buildWB_kernel(
    const float* __restrict__ x, const float* __restrict__ Ws,
    const float* __restrict__ Wb, const float* __restrict__ Wg,
    float* Wcomb, const float* __restrict__ biasC, float* __restrict__ C)
{
    __shared__ __align__(16) float smem[8192];

    const int tid = threadIdx.x;

    if (blockIdx.x < 512) {
        // ---------------- buildW_B: WW fold + gate copy ----------------
        float* wsrow = smem;          // Ws row d   (4096)
        float* wbs   = smem + 4096;   // Wb[pr][j]  (4096)

        const int d = blockIdx.x;
        #pragma unroll
        for (int i = 0; i < 16; ++i) {
            wsrow[i * 256 + tid] = Ws[(size_t)d * 4096 + i * 256 + tid];
            wbs[i * 256 + tid]   = Wb[i * 256 + tid];
        }
        __syncthreads();

        float* wrow = Wcomb + (size_t)d * NC_;

        // WW: 4 cols/thread, 128 FMA each
        #pragma unroll
        for (int ii = 0; ii < 4; ++ii) {
            const int g = ii * 256 + tid;
            const int l = g >> 5, j = g & 31;
            float acc = 0.f;
            #pragma unroll 8
            for (int pr = 0; pr < 128; ++pr)
                acc = fmaf(wsrow[l * 128 + pr], wbs[pr * 32 + j], acc);
            wrow[1024 + g] = acc;
        }
        // gate copy: 2 cols/thread
        #pragma unroll
        for (int ii = 0; ii < 2; ++ii) {
            const int c = ii * 256 + tid;
            wrow[2048 + c] = Wg[(size_t)d * 512 + c];
        }
        return;
    }

    // ---------------- gemm1: 64x64 tile, 4x4 acc/thread ----------------
    float (*As)[68] = (float(*)[68])smem;             // 32*68 = 2176
    float (*Bs)[64] = (float(*)[64])(smem + 32 * 68); // 32*64 = 2048

    const int g  = blockIdx.x - 512;
    const int m0 = (g >> 4) * 64;          // 64 row-tiles
    const int n0 = (g & 15) * 64;          // 16 col-tiles (cols 0..1024)
    const int tx = tid & 15;
    const int ty = tid >> 4;
    const int K = D_, N = NC_;

    float c[4][4] = {};

    for (int k0 = 0; k0 < K; k0 += 32) {
        {
            const int o = tid * 8;
            const int m = o >> 5;
            const int k = o & 31;
            const float* ap = x + (size_t)(m0 + m) * K + k0 + k;
            const float4 a0 = *(const float4*)ap;
            const float4 a1 = *(const float4*)(ap + 4);
            As[k + 0][m] = a0.x; As[k + 1][m] = a0.y;
            As[k + 2][m] = a0.z; As[k + 3][m] = a0.w;
            As[k + 4][m] = a1.x; As[k + 5][m] = a1.y;
            As[k + 6][m] = a1.z; As[k + 7][m] = a1.w;
        }
        {
            const int o = tid * 8;
            const int k = o >> 6;
            const int n = o & 63;
            const float* bp = Wcomb + (size_t)(k0 + k) * N + n0 + n;
            *(float4*)&Bs[k][n]     = *(const float4*)bp;
            *(float4*)&Bs[k][n + 4] = *(const float4*)(bp + 4);
        }
        __syncthreads();

        #pragma unroll
        for (int kk = 0; kk < 32; ++kk) {
            const float4 av = *(const float4*)&As[kk][ty * 4];
            const float4 bv = *(const float4*)&Bs[kk][tx * 4];
            const float a[4] = {av.x, av.y, av.z, av.w};
            const float b[4] = {bv.x, bv.y, bv.z, bv.w};
            #pragma unroll
            for (int i = 0; i < 4; ++i)
                #pragma unroll
                for (int j = 0; j < 4; ++j)
                    c[i][j] = fmaf(a[i], b[j], c[i][j]);
        }
        __syncthreads();
    }

    const float4 bv = *(const float4*)&biasC[n0 + tx * 4];
    #pragma unroll
    for (int i = 0; i < 4; ++i) {
        float4 outv;
        outv.x = c[i][0] + bv.x;
        outv.y = c[i][1] + bv.y;
        outv.z = c[i][2] + bv.z;
        outv.w = c[i][3] + bv.w;
        *(float4*)&C[(size_t)(m0 + ty * 4 + i) * N + n0 + tx * 4] = outv;
    }
}

// ---------------------------------------------------------------------------
// GEMM tile body for the fused kernel (128x128 tile, 8x8 acc/thread).
// ---------------------------------------------------------------------------
__device__ __forceinline__ void gemm_tile_body(
    const float* __restrict__ A, const float* __restrict__ Bm,
    const float* __restrict__ bias, float* __restrict__ C,
    int M, int N, int K, int m0, int n0,
    float (*As)[132], float (*Bs)[132])
{
    const int tid = threadIdx.x;
    const int tx = tid & 15;        // col group (n)
    const int ty = tid >> 4;        // row group (m)

    float acc[8][8] = {};

    for (int k0 = 0; k0 < K; k0 += 32) {
        // A tile: 128 rows x 32 k, write transposed As[k][m]
        #pragma unroll
        for (int p = 0; p < 4; ++p) {
            const int m = (tid >> 3) + 32 * p;
            const int k = (tid & 7) * 4;
            const float4 av = *(const float4*)(A + (size_t)(m0 + m) * K + k0 + k);
            As[k + 0][m] = av.x;
            As[k + 1][m] = av.y;
            As[k + 2][m] = av.z;
            As[k + 3][m] = av.w;
        }
        // B tile: 32 k x 128 n
        #pragma unroll
        for (int p = 0; p < 2; ++p) {
            const int k = (tid >> 4) + 16 * p;
            const int n = (tid & 15) * 8;
            const float* bp = Bm + (size_t)(k0 + k) * N + n0 + n;
            *(float4*)&Bs[k][n]     = *(const float4*)bp;
            *(float4*)&Bs[k][n + 4] = *(const float4*)(bp + 4);
        }
        __syncthreads();

        #pragma unroll
        for (int kk = 0; kk < 32; ++kk) {
            const float4 a0 = *(const float4*)&As[kk][ty * 8];
            const float4 a1 = *(const float4*)&As[kk][ty * 8 + 4];
            const float4 b0 = *(const float4*)&Bs[kk][tx * 8];
            const float4 b1 = *(const float4*)&Bs[kk][tx * 8 + 4];
            const float a[8] = {a0.x, a0.y, a0.z, a0.w, a1.x, a1.y, a1.z, a1.w};
            const float b[8] = {b0.x, b0.y, b0.z, b0.w, b1.x, b1.y, b1.z, b1.w};
            #pragma unroll
            for (int i = 0; i < 8; ++i)
                #pragma unroll
                for (int j = 0; j < 8; ++j)
                    acc[i][j] = fmaf(a[i], b[j], acc[i][j]);
        }
        __syncthreads();
    }

    const float4 bv0 = *(const float4*)&bias[n0 + tx * 8];
    const float4 bv1 = *(const float4*)&bias[n0 + tx * 8 + 4];
    #pragma unroll
    for (int i = 0; i < 8; ++i) {
        float* cp = C + (size_t)(m0 + ty * 8 + i) * N + n0 + tx * 8;
        float4 o0, o1;
        o0.x = acc[i][0] + bv0.x; o0.y = acc[i][1] + bv0.y;
        o0.z = acc[i][2] + bv0.z; o0.w = acc[i][3] + bv0.w;
        o1.x = acc[i][4] + bv1.x; o1.y = acc[i][5] + bv1.y;
        o1.z = acc[i][6] + bv1.z; o1.w = acc[i][7] + bv1.w;
        *(float4*)cp       = o0;
        *(float4*)(cp + 4) = o1;
    }
}

// ---------------------------------------------------------------------------
// cvec: c[bt][r] = sum_l u[l]*Abar[l][r], u = x[bt,0:32]. AbarI is the
// interleaved block at C[bt*NC_ + 0..1024). One wave per bt.
// ---------------------------------------------------------------------------
__global__ __launch_bounds__(256) void cvec_kernel(
    const float* __restrict__ Cc, const float* __restrict__ x,
    float* __restrict__ cBuf)
{
    const int tid  = threadIdx.x;
    const int lane = tid & 63;
    const int bt   = blockIdx.x * 4 + (tid >> 6);

    const float* base = Cc + (size_t)bt * NC_ + 4 * lane;
    float4 a0 = *(const float4*)(base + 0);
    float4 a1 = *(const float4*)(base + 256);
    float4 a2 = *(const float4*)(base + 512);
    float4 a3 = *(const float4*)(base + 768);

    const float u = x[(size_t)bt * D_ + (lane & 31)];
    const int idx0 = 16 * (lane & 7);
    const float u0 = bpermute_f(idx0 + 0,  u);
    const float u1 = bpermute_f(idx0 + 4,  u);
    const float u2 = bpermute_f(idx0 + 8,  u);
    const float u3 = bpermute_f(idx0 + 12, u);

    float p0 = fmaf(u3, a0.w, fmaf(u2, a0.z, fmaf(u1, a0.y, u0 * a0.x)));
    float p1 = fmaf(u3, a1.w, fmaf(u2, a1.z, fmaf(u1, a1.y, u0 * a1.x)));
    float p2 = fmaf(u3, a2.w, fmaf(u2, a2.z, fmaf(u1, a2.y, u0 * a2.x)));
    float p3 = fmaf(u3, a3.w, fmaf(u2, a3.z, fmaf(u1, a3.y, u0 * a3.x)));

    p0 = octet_sum(p0); p1 = octet_sum(p1);
    p2 = octet_sum(p2); p3 = octet_sum(p3);

    if ((lane & 7) == 7) {          // top lane of octet k holds m[k+8q]
        const int k = lane >> 3;
        float* cp = cBuf + (size_t)bt * 32 + k;
        cp[0]  = p0;
        cp[8]  = p1;
        cp[16] = p2;
        cp[24] = p3;
    }
}

// ---------------------------------------------------------------------------
// FUSED: serial scan (blocks 0..3, tid<64) + GEMM part 2 (blocks 4..387,
// C columns [1024, 2560) = G + gate). The scan reads C cols [0,1024) and
// cBuf (both finalized by prior dispatches); the GEMM writes cols
// [1024,2560) -- fully disjoint, no inter-block dependency. During the
// scan's ~199 us (4 waves) the 384 GEMM blocks fill the idle CUs
// (measured round 10/12/13: fused dispatch 220-231 us vs 199 us scan-solo).
//
// s_setprio(3) on the scan wave: the 21 us fused-vs-solo delta is scan
// slowdown from sharing CUs with gemm2 waves. Raising the scan wave's
// priority makes it win issue arbitration the moment its prefetched loads
// land (T5 regime: independent latency-critical wave vs throughput waves).
//
// Scan recurrence (one wave per batch, verified round-0 machinery):
//   w_{t+1} = (w_t . Abar_t) * rsqrt(sum w_t^2) + c_t
// ---------------------------------------------------------------------------
__global__ __launch_bounds__(256) void fused_scan_gemm2_kernel(
    const float* __restrict__ x, const float* __restrict__ Wcomb,
    const float* __restrict__ biasC, float* __restrict__ Cc,
    const float* __restrict__ cBuf, float* __restrict__ wOut)
{
    __shared__ float As[32][132];
    __shared__ float Bs[32][132];

    if (blockIdx.x < 4) {
        // ------------------ scan path (threads 0..63 only) ------------------
        const int tid = threadIdx.x;
        if (tid >= 64) return;
        __builtin_amdgcn_s_setprio(3);   // latency-critical wave: win arbitration
        const int b = blockIdx.x;

        const float* At = Cc + (size_t)b * L_ * NC_ + 4 * tid;   // lane base
        const float* cb = cBuf + (size_t)b * L_ * 32 + (tid & 31);
        float*       wo = wOut + (size_t)b * L_ * 64 + tid;

        const int idx0 = 16 * (tid & 7);
        const int idxR = 32 * (tid & 7) + 28;    // octet TOP lane
        const bool selA = (tid >> 3) & 1;
        const bool selB = (tid >> 4) & 1;

        float4 areg[DPRE][4];
        float  creg[DPRE];

        #pragma unroll
        for (int j = 0; j < DPRE; ++j) {
            const float* ap = At + (size_t)j * NC_;
            #pragma unroll
            for (int q = 0; q < 4; ++q) areg[j][q] = *(const float4*)(ap + 256 * q);
            creg[j] = cb[j * 32];
        }

        float w = 0.f;   // w_0 = 0  (h_0 = 0)

        for (int t = 0; t < L_; t += DPRE) {
            #pragma unroll
            for (int j = 0; j < DPRE; ++j) {
                wo[(t + j) * 64] = w;

                float red = reduce32_to_lane31(w * w);

                const float wb0 = bpermute_f(idx0 + 0,  w);
                const float wb1 = bpermute_f(idx0 + 4,  w);
                const float wb2 = bpermute_f(idx0 + 8,  w);
                const float wb3 = bpermute_f(idx0 + 12, w);

                float p0, p1, p2, p3;
                {
                    const float4 a0 = areg[j][0], a1 = areg[j][1];
                    const float4 a2 = areg[j][2], a3 = areg[j][3];
                    p0 = fmaf(wb3, a0.w, fmaf(wb2, a0.z, fmaf(wb1, a0.y, wb0 * a0.x)));
                    p1 = fmaf(wb3, a1.w, fmaf(wb2, a1.z, fmaf(wb1, a1.y, wb0 * a1.x)));
                    p2 = fmaf(wb3, a2.w, fmaf(wb2, a2.z, fmaf(wb1, a2.y, wb0 * a2.x)));
                    p3 = fmaf(wb3, a3.w, fmaf(wb2, a3.z, fmaf(wb1, a3.y, wb0 * a3.x)));
                }

                p0 = octet_sum(p0);
                p1 = octet_sum(p1);
                p2 = octet_sum(p2);
                p3 = octet_sum(p3);

                const float m0 = bpermute_f(idxR, p0);
                const float m1 = bpermute_f(idxR, p1);
                const float m2 = bpermute_f(idxR, p2);
                const float m3 = bpermute_f(idxR, p3);
                const float t0 = selA ? m1 : m0;
                const float t1 = selA ? m3 : m2;
                const float m  = selB ? t1 : t0;

                const float n2 = readlane_f(red, 31);
                const float rn = rsqrtf(n2 + 1e-24f);
                w = fmaf(m, rn, creg[j]);

                int tn = t + j + DPRE;
                if (tn > L_ - 1) tn = L_ - 1;
                const float* ap = At + (size_t)tn * NC_;
                #pragma unroll
                for (int q = 0; q < 4; ++q) areg[j][q] = *(const float4*)(ap + 256 * q);
                creg[j] = cb[tn * 32];
            }
        }
        return;
    }

    // ------------------ GEMM part-2 path (cols 1024..2560) ------------------
    const int g  = blockIdx.x - 4;
    const int m0 = (g / 12) * 128;
    const int n0 = 1024 + (g % 12) * 128;
    gemm_tile_body(x, Wcomb, biasC, Cc, BT_, NC_, D_, m0, n0, As, Bs);
}

// ---------------------------------------------------------------------------
// FUSED phaseB + epilogue (one block per bt, 256 threads):
//   lf = w/||w|| + u                       (threads 0..63)
//   y1[j] = sum_l lf[l]*G[l*32+j] + bb[j]  (8 groups x 32, G in C cols 1024+)
//   y = y1 @ W_out + b_out; LayerNorm; gated residual (gate from C cols 2048+)
// ---------------------------------------------------------------------------
__global__ __launch_bounds__(256) void phaseB_epilogue_kernel(
    const float* __restrict__ Cc, const float* __restrict__ x,
    const float* __restrict__ wBuf, const float* __restrict__ bb,
    const float* __restrict__ Wout, const float* __restrict__ bout,
    const float* __restrict__ gamma, const float* __restrict__ beta,
    float* __restrict__ out)
{
    __shared__ float lf[32];
    __shared__ float part[8][32];
    __shared__ float ys[32];
    __shared__ float red1[4], red2[4];

    const int bt = blockIdx.x;
    const int tid = threadIdx.x;

    if (tid < 64) {
        const float wv = wBuf[(size_t)bt * 64 + tid];
        float red = reduce32_to_lane31(wv * wv);
        const float n2 = readlane_f(red, 31);
        const float rn = rsqrtf(n2 + 1e-24f);
        if (tid < 32)
            lf[tid] = fmaf(wv, rn, x[(size_t)bt * D_ + tid]);  // left = h + u
    }
    __syncthreads();

    {
        const int j = tid & 31, q = tid >> 5;   // q in 0..7, 4 l's each
        const float* Gp = Cc + (size_t)bt * NC_ + 1024;
        float p = 0.f;
        #pragma unroll
        for (int i = 0; i < 4; ++i)
            p = fmaf(lf[4 * q + i], Gp[(4 * q + i) * 32 + j], p);
        part[q][j] = p;
    }
    __syncthreads();

    if (tid < 32) {
        float s = bb[tid];
        #pragma unroll
        for (int q = 0; q < 8; ++q) s += part[q][tid];
        ys[tid] = s;
    }
    __syncthreads();

    float yv[2];
    #pragma unroll
    for (int q = 0; q < 2; ++q) {
        const int d = tid + q * 256;
        float acc = bout[d];
        #pragma unroll
        for (int j = 0; j < 32; ++j)
            acc = fmaf(ys[j], Wout[j * D_ + d], acc);
        yv[q] = acc;
    }

    float s1 = yv[0] + yv[1];
    float s2 = yv[0] * yv[0] + yv[1] * yv[1];
    #pragma unroll
    for (int m = 1; m <= 32; m <<= 1) {
        s1 += __shfl_xor(s1, m);
        s2 += __shfl_xor(s2, m);
    }
    const int wid = tid >> 6;
    if ((tid & 63) == 0) { red1[wid] = s1; red2[wid] = s2; }
    __syncthreads();
    const float S1 = red1[0] + red1[1] + red1[2] + red1[3];
    const float S2 = red2[0] + red2[1] + red2[2] + red2[3];
    const float mu  = S1 * (1.f / (float)D_);
    const float var = S2 * (1.f / (float)D_) - mu * mu;
    const float rstd = rsqrtf(var + 1e-6f);

    #pragma unroll
    for (int q = 0; q < 2; ++q) {
        const int d = tid + q * 256;
        const size_t gi = (size_t)bt * D_ + d;
        const float yn = (yv[q] - mu) * rstd * gamma[d] + beta[d];
        const float z = Cc[(size_t)bt * NC_ + 2048 + d];
        const float g = 1.f / (1.f + expf(-z));
        const float xv = x[gi];
        out[gi] = g * yn + (1.f - g) * xv;
    }
}

// ---------------------------------------------------------------------------
extern "C" void kernel_launch(void* const* d_in, const int* in_sizes, int n_in,
                              void* d_out, int out_size, void* d_ws, size_t ws_size,
                              hipStream_t stream)
{
    const float* x        = (const float*)d_in[0];
    const float* W_site   = (const float*)d_in[1];
    const float* b_site   = (const float*)d_in[2];
    const float* W_bridge = (const float*)d_in[3];
    const float* b_bridge = (const float*)d_in[4];
    const float* W_out    = (const float*)d_in[5];
    const float* b_out    = (const float*)d_in[6];
    const float* gamma    = (const float*)d_in[7];
    const float* beta     = (const float*)d_in[8];
    const float* W_gate   = (const float*)d_in[9];
    const float* b_gate   = (const float*)d_in[10];
    float* out = (float*)d_out;

    float* ws = (float*)d_ws;
    float* Wcomb = ws;                            //   512*2560 = 1,310,720 f
    float* biasC = Wcomb + (size_t)512 * NC_;     //        2,560 f
    float* Cc    = biasC + NC_;                   // 4096*2560 = 10,485,760 f (42 MB)
    float* cBuf  = Cc    + (size_t)BT_ * NC_;     //      131,072 f
    float* wBuf  = cBuf  + (size_t)BT_ * 32;      //      262,144 f

    // 0. buildW_A: WA fold (cols 0..1024) + all biases
    buildWA_kernel<<<dim3(513), dim3(256), 0, stream>>>(
        W_site, b_site, W_bridge, b_gate, Wcomb, biasC);

    // 1. gemm1 (C cols [0,1024) = AbarI, 64^2 tiles) + buildW_B (WW fold +
    //    gate copy, Wcomb cols [1024,2560)) in one dispatch -- disjoint work.
    gemm1_buildWB_kernel<<<dim3(512 + 1024), dim3(256), 0, stream>>>(
        x, W_site, W_bridge, W_gate, Wcomb, biasC, Cc);

    // 2. c vectors: c = u . Abar  (fully parallel)
    cvec_kernel<<<dim3(BT_ / 4), dim3(256), 0, stream>>>(Cc, x, cBuf);

    // 3. FUSED: scan (blocks 0..3, setprio(3)) + GEMM part 2 (cols
    //    1024..2560, blocks 4..387) -- part 2 hides under the scan.
    fused_scan_gemm2_kernel<<<dim3(4 + 12 * (BT_ / 128)), dim3(256), 0, stream>>>(
        x, Wcomb, biasC, Cc, cBuf, wBuf);

    // 4. FUSED phaseB + epilogue
    phaseB_epilogue_kernel<<<dim3(BT_), dim3(256), 0, stream>>>(
        Cc, x, wBuf, b_bridge, W_out, b_out, gamma, beta, out);
}